// Round 1
// 886.357 us; speedup vs baseline: 1.0350x; 1.0350x over previous
//
#include <hip/hip_runtime.h>
#include <hip/hip_bf16.h>
#include <stdint.h>

#define B_ 64
#define S_ 2048
#define H_ 1024
#define X0_ 1024
#define X1_ 512
#define X2_ 512
#define A_ 512

typedef __attribute__((ext_vector_type(8))) short short8;
typedef __attribute__((ext_vector_type(8))) __bf16 bf16x8;
typedef __attribute__((ext_vector_type(4))) float floatx4;

typedef __attribute__((address_space(1))) const void glb_cv;
typedef __attribute__((address_space(3))) void lds_v;

__device__ inline unsigned short f2bf(float f) {
    union { float f; unsigned u; } v; v.f = f;
    unsigned u = v.u;
    unsigned r = u + 0x7FFF + ((u >> 16) & 1);  // RNE
    return (unsigned short)(r >> 16);
}

// HW bf16 convert (RNE) — compiler pairs these into v_cvt_pk_bf16_f32.
__device__ inline short hwbf(float f) {
    return (short)__builtin_bit_cast(unsigned short, __float2bfloat16(f));
}

// ---------------- K0a: convert Wh (A x H fp32) -> bf16 bits ----------------
__global__ void k_convert_wh(const float* __restrict__ wh, unsigned short* __restrict__ whb) {
    int i = (blockIdx.x * 256 + threadIdx.x) * 4;
    float4 f = *(const float4*)(wh + i);
    ushort4 o;
    o.x = f2bf(f.x); o.y = f2bf(f.y); o.z = f2bf(f.z); o.w = f2bf(f.w);
    *(ushort4*)(whb + i) = o;
}

// ---------------- K1: ctx[b,a] = bias[a] + W0 x0 + W1 x1 + W2 x2 ----------
__global__ void k_ctx(const float* __restrict__ x0, const float* __restrict__ x1,
                      const float* __restrict__ x2, const float* __restrict__ w0,
                      const float* __restrict__ w1, const float* __restrict__ w2,
                      const float* __restrict__ bias, float* __restrict__ ctx) {
    __shared__ float xs[X0_ + X1_ + X2_];
    int b = blockIdx.x >> 4;
    int a0 = (blockIdx.x & 15) << 5;
    int t = threadIdx.x;
    for (int i = t; i < X0_; i += 256) xs[i] = x0[b * X0_ + i];
    for (int i = t; i < X1_; i += 256) xs[X0_ + i] = x1[b * X1_ + i];
    for (int i = t; i < X2_; i += 256) xs[X0_ + X1_ + i] = x2[b * X2_ + i];
    __syncthreads();
    int wave = t >> 6, lane = t & 63;
    for (int j = 0; j < 8; j++) {
        int a = a0 + wave * 8 + j;
        float acc = 0.f;
        const float* r0 = w0 + (size_t)a * X0_;
        for (int k = lane; k < X0_; k += 64) acc += r0[k] * xs[k];
        const float* r1 = w1 + (size_t)a * X1_;
        for (int k = lane; k < X1_; k += 64) acc += r1[k] * xs[X0_ + k];
        const float* r2 = w2 + (size_t)a * X2_;
        for (int k = lane; k < X2_; k += 64) acc += r2[k] * xs[X0_ + X1_ + k];
        for (int off = 32; off; off >>= 1) acc += __shfl_down(acc, off, 64);
        if (lane == 0) ctx[b * A_ + a] = acc + bias[a];
    }
}

// ---------------- K2: 128x128 GEMM -> partial scores (fused fp32->bf16 A) --
// blockIdx.x = b*64 + mt*4 + nblk. Block computes Ah tile [128 s] x [128 a],
// epilogue: relu(Ah+ctx)*v reduced over the 128 a -> partial[nblk][b][s].
// A is reg-staged from fp32 hidden (global->reg->cvt->LDS), software-pipelined
// one K-step ahead so HBM latency hides under ds_read+MFMA. B (whb, 1 MB,
// L2-resident) stays on the global_load_lds width=16 path.
__launch_bounds__(256, 2)
__global__ void k_scores(const float* __restrict__ hidden, const unsigned short* __restrict__ whb,
                         const float* __restrict__ ctx, const float* __restrict__ vw,
                         const int* __restrict__ lengths, float* __restrict__ partial) {
    int b = blockIdx.x >> 6;
    int mt = (blockIdx.x >> 2) & 15;
    int nblk = blockIdx.x & 3;
    int s0 = mt * 128;
    if (s0 >= lengths[b]) return;
    int n0b = nblk * 128;

    __shared__ unsigned short As[128 * 32];  // [row][k] bf16, rows 64B
    __shared__ unsigned short Bs[128 * 32];  // [n][k] bf16
    __shared__ float sred[4][64];

    int t = threadIdx.x;
    int wv = t >> 6, lane = t & 63;
    int nl = lane & 15, quad = lane >> 4;
    int wm0 = (wv & 1) * 64;
    int wn0 = (wv >> 1) * 64;

    // A-chunk mapping: chunk c = 16B of As (row = c>>2, k-quarter = c&3).
    int c0 = wv * 64 + lane;    // chunks 0..255
    int c1 = c0 + 256;          // chunks 256..511
    const float* abase = hidden + (size_t)(b * S_ + s0) * H_;
    const unsigned short* bbase = whb + (size_t)n0b * H_;
    size_t aoff0 = (size_t)(c0 >> 2) * H_ + (c0 & 3) * 8;
    size_t aoff1 = (size_t)(c1 >> 2) * H_ + (c1 & 3) * 8;

    // prologue: prefetch k0=0 A-chunks into regs
    float4 a0a = *(const float4*)(abase + aoff0);
    float4 a0b = *(const float4*)(abase + aoff0 + 4);
    float4 a1a = *(const float4*)(abase + aoff1);
    float4 a1b = *(const float4*)(abase + aoff1 + 4);

    floatx4 acc[4][4];
#pragma unroll
    for (int i = 0; i < 4; i++)
#pragma unroll
        for (int j = 0; j < 4; j++) acc[i][j] = (floatx4){0.f, 0.f, 0.f, 0.f};

    for (int k0 = 0; k0 < H_; k0 += 32) {
        // stage B first (start its vmcnt latency early)
#pragma unroll
        for (int i = 0; i < 2; i++) {
            int c = wv * 64 + i * 256 + lane;
            const unsigned short* gb = bbase + (size_t)(c >> 2) * H_ + k0 + (c & 3) * 8;
            __builtin_amdgcn_global_load_lds((glb_cv*)gb,
                (lds_v*)(Bs + (wv * 64 + i * 256) * 8), 16, 0, 0);
        }
        // convert prefetched A regs -> bf16, write LDS (conflict-free linear b128)
        short8 pa, pb;
        pa[0] = hwbf(a0a.x); pa[1] = hwbf(a0a.y); pa[2] = hwbf(a0a.z); pa[3] = hwbf(a0a.w);
        pa[4] = hwbf(a0b.x); pa[5] = hwbf(a0b.y); pa[6] = hwbf(a0b.z); pa[7] = hwbf(a0b.w);
        pb[0] = hwbf(a1a.x); pb[1] = hwbf(a1a.y); pb[2] = hwbf(a1a.z); pb[3] = hwbf(a1a.w);
        pb[4] = hwbf(a1b.x); pb[5] = hwbf(a1b.y); pb[6] = hwbf(a1b.z); pb[7] = hwbf(a1b.w);
        *(short8*)&As[c0 * 8] = pa;
        *(short8*)&As[c1 * 8] = pb;
        __syncthreads();  // drains vmcnt (B) + lgkm (A writes)

        // prefetch A for next K-step: issue now, consumed after next barrier,
        // latency hides under the ds_read+MFMA below.
        if (k0 + 32 < H_) {
            a0a = *(const float4*)(abase + aoff0 + k0 + 32);
            a0b = *(const float4*)(abase + aoff0 + k0 + 36);
            a1a = *(const float4*)(abase + aoff1 + k0 + 32);
            a1b = *(const float4*)(abase + aoff1 + k0 + 36);
        }

        short8 af[4];
#pragma unroll
        for (int m = 0; m < 4; m++)
            af[m] = *(const short8*)&As[(wm0 + m * 16 + nl) * 32 + quad * 8];
#pragma unroll
        for (int n = 0; n < 4; n++) {
            short8 bfr = *(const short8*)&Bs[(wn0 + n * 16 + nl) * 32 + quad * 8];
            bf16x8 bfv = __builtin_bit_cast(bf16x8, bfr);
#pragma unroll
            for (int m = 0; m < 4; m++) {
                bf16x8 afv = __builtin_bit_cast(bf16x8, af[m]);
                acc[m][n] = __builtin_amdgcn_mfma_f32_16x16x32_bf16(afv, bfv, acc[m][n], 0, 0, 0);
            }
        }
        __syncthreads();  // protect LDS before next stage
    }

    // epilogue: relu(acc + ctx)*v, reduce over this block's 128 n
    float cv[4], cc[4];
#pragma unroll
    for (int n = 0; n < 4; n++) {
        int gn = n0b + wn0 + n * 16 + nl;
        cv[n] = vw[gn];
        cc[n] = ctx[b * A_ + gn];
    }
#pragma unroll
    for (int m = 0; m < 4; m++) {
#pragma unroll
        for (int r = 0; r < 4; r++) {
            float sv = 0.f;
#pragma unroll
            for (int n = 0; n < 4; n++) {
                float x = acc[m][n][r] + cc[n];
                sv += (x > 0.f) ? x * cv[n] : 0.f;
            }
#pragma unroll
            for (int off = 1; off < 16; off <<= 1) sv += __shfl_xor(sv, off, 16);
            if (nl == 0) sred[wv][m * 16 + quad * 4 + r] = sv;
        }
    }
    __syncthreads();
    if (t < 128) {
        int h = t >> 6;
        float s = sred[h][t & 63] + sred[h + 2][t & 63];
        partial[((size_t)nblk * B_ + b) * S_ + s0 + t] = s;
    }
}

// ---------------- K3: sum partials, masked softmax over S per b ------------
__global__ void k_softmax(const float* __restrict__ partial, const int* __restrict__ lengths,
                          float* __restrict__ scores, float* __restrict__ probs) {
    int b = blockIdx.x;
    int len = lengths[b];
    int t = threadIdx.x;
    __shared__ float red[256];
    float mx = -1e30f;
    for (int s = t; s < len; s += 256) {
        float sc = partial[(size_t)b * S_ + s] + partial[((size_t)B_ + b) * S_ + s] +
                   partial[((size_t)2 * B_ + b) * S_ + s] + partial[((size_t)3 * B_ + b) * S_ + s];
        scores[b * S_ + s] = sc;
        mx = fmaxf(mx, sc);
    }
    red[t] = mx; __syncthreads();
    for (int off = 128; off; off >>= 1) {
        if (t < off) red[t] = fmaxf(red[t], red[t + off]);
        __syncthreads();
    }
    mx = red[0]; __syncthreads();
    float sum = 0.f;
    for (int s = t; s < len; s += 256) sum += __expf(scores[b * S_ + s] - mx);
    red[t] = sum; __syncthreads();
    for (int off = 128; off; off >>= 1) {
        if (t < off) red[t] += red[t + off];
        __syncthreads();
    }
    float inv = 1.f / red[0];
    for (int s = t; s < S_; s += 256)
        probs[b * S_ + s] = (s < len) ? __expf(scores[b * S_ + s] - mx) * inv : 0.f;
}

// ---------------- K4: partial_out[ch][b][h] = sum_{s in chunk} p[s]*hidden -
__global__ void k_weighted(const float* __restrict__ hidden, const float* __restrict__ probs,
                           const int* __restrict__ lengths, float* __restrict__ partial) {
    int blk = blockIdx.x;
    int b = blk >> 4, ch = blk & 15;
    int len = lengths[b];
    int s0 = ch * 128;
    if (s0 >= len) return;
    int send = min(s0 + 128, len);
    int t = threadIdx.x;
    float4 acc = {0.f, 0.f, 0.f, 0.f};
    const float* hb = hidden + (size_t)(b * S_ + s0) * H_ + t * 4;
    const float* pb = probs + b * S_;
    int s = s0;
    for (; s + 1 < send; s += 2) {
        float p0 = pb[s], p1 = pb[s + 1];
        float4 h0 = *(const float4*)hb;
        float4 h1 = *(const float4*)(hb + H_);
        acc.x += p0 * h0.x + p1 * h1.x;
        acc.y += p0 * h0.y + p1 * h1.y;
        acc.z += p0 * h0.z + p1 * h1.z;
        acc.w += p0 * h0.w + p1 * h1.w;
        hb += 2 * H_;
    }
    if (s < send) {
        float p = pb[s];
        float4 h = *(const float4*)hb;
        acc.x += p * h.x; acc.y += p * h.y; acc.z += p * h.z; acc.w += p * h.w;
    }
    *(float4*)(partial + ((size_t)ch * B_ + b) * H_ + t * 4) = acc;
}

// ---------------- K5: out[b][h] = sum over valid chunks -------------------
__global__ void k_reduce(const float* __restrict__ partial, const int* __restrict__ lengths,
                         float* __restrict__ out) {
    int i = blockIdx.x * 256 + threadIdx.x;
    int b = i >> 10;
    int h = i & 1023;
    int len = lengths[b];
    int nch = (len + 127) >> 7;
    float s = 0.f;
    for (int c = 0; c < nch; c++) s += partial[((size_t)c * B_ + b) * H_ + h];
    out[i] = s;
}

extern "C" void kernel_launch(void* const* d_in, const int* in_sizes, int n_in,
                              void* d_out, int out_size, void* d_ws, size_t ws_size,
                              hipStream_t stream) {
    const float* hidden = (const float*)d_in[0];
    const float* x0 = (const float*)d_in[1];
    const float* x1 = (const float*)d_in[2];
    const float* x2 = (const float*)d_in[3];
    const int* lengths = (const int*)d_in[4];
    const float* wh_w = (const float*)d_in[5];
    const float* wh_b = (const float*)d_in[6];
    const float* w0_w = (const float*)d_in[7];
    const float* w1_w = (const float*)d_in[8];
    const float* w2_w = (const float*)d_in[9];
    const float* v_w = (const float*)d_in[10];

    float* out = (float*)d_out;    // [B,H]
    float* probs = out + B_ * H_;  // [B,S]

    char* ws = (char*)d_ws;
    float* ctx = (float*)ws;                                    // 128 KB
    unsigned short* whb = (unsigned short*)(ws + (1 << 17));    // 1 MB
    float* scores = (float*)(ws + (1 << 17) + (1 << 20));       // 512 KB
    float* pscore = (float*)(ws + (1 << 17) + (1 << 20) + (1 << 19));          // 2 MB  [4][B][S]
    float* pout = (float*)(ws + (1 << 17) + (1 << 20) + (1 << 19) + (1 << 21)); // 4 MB  [16][B][H]

    k_convert_wh<<<dim3(A_ * H_ / 1024), dim3(256), 0, stream>>>(wh_w, whb);
    k_ctx<<<dim3(B_ * (A_ / 32)), dim3(256), 0, stream>>>(x0, x1, x2, w0_w, w1_w, w2_w, wh_b, ctx);
    k_scores<<<dim3(B_ * 64), dim3(256), 0, stream>>>(hidden, whb, ctx, v_w, lengths, pscore);
    k_softmax<<<dim3(B_), dim3(256), 0, stream>>>(pscore, lengths, scores, probs);
    k_weighted<<<dim3(B_ * 16), dim3(256), 0, stream>>>(hidden, probs, lengths, pout);
    k_reduce<<<dim3(B_ * H_ / 256), dim3(256), 0, stream>>>(pout, lengths, out);
}

// Round 2
// 846.957 us; speedup vs baseline: 1.0832x; 1.0465x over previous
//
#include <hip/hip_runtime.h>
#include <hip/hip_bf16.h>
#include <stdint.h>

#define B_ 64
#define S_ 2048
#define H_ 1024
#define X0_ 1024
#define X1_ 512
#define X2_ 512
#define A_ 512

typedef __attribute__((ext_vector_type(8))) short short8;
typedef __attribute__((ext_vector_type(8))) __bf16 bf16x8;
typedef __attribute__((ext_vector_type(4))) float floatx4;

typedef __attribute__((address_space(1))) const void glb_cv;
typedef __attribute__((address_space(3))) void lds_v;

__device__ inline unsigned short f2bf(float f) {
    union { float f; unsigned u; } v; v.f = f;
    unsigned u = v.u;
    unsigned r = u + 0x7FFF + ((u >> 16) & 1);  // RNE
    return (unsigned short)(r >> 16);
}

// HW bf16 convert (RNE) — compiler pairs these into v_cvt_pk_bf16_f32.
__device__ inline short hwbf(float f) {
    return (short)__builtin_bit_cast(unsigned short, __float2bfloat16(f));
}

// ---------------- K0a: convert Wh (A x H fp32) -> bf16 bits ----------------
__global__ void k_convert_wh(const float* __restrict__ wh, unsigned short* __restrict__ whb) {
    int i = (blockIdx.x * 256 + threadIdx.x) * 4;
    float4 f = *(const float4*)(wh + i);
    ushort4 o;
    o.x = f2bf(f.x); o.y = f2bf(f.y); o.z = f2bf(f.z); o.w = f2bf(f.w);
    *(ushort4*)(whb + i) = o;
}

// ---------------- K1: ctx[b,a] = bias[a] + W0 x0 + W1 x1 + W2 x2 ----------
__global__ void k_ctx(const float* __restrict__ x0, const float* __restrict__ x1,
                      const float* __restrict__ x2, const float* __restrict__ w0,
                      const float* __restrict__ w1, const float* __restrict__ w2,
                      const float* __restrict__ bias, float* __restrict__ ctx) {
    __shared__ float xs[X0_ + X1_ + X2_];
    int b = blockIdx.x >> 4;
    int a0 = (blockIdx.x & 15) << 5;
    int t = threadIdx.x;
    for (int i = t; i < X0_; i += 256) xs[i] = x0[b * X0_ + i];
    for (int i = t; i < X1_; i += 256) xs[X0_ + i] = x1[b * X1_ + i];
    for (int i = t; i < X2_; i += 256) xs[X0_ + X1_ + i] = x2[b * X2_ + i];
    __syncthreads();
    int wave = t >> 6, lane = t & 63;
    for (int j = 0; j < 8; j++) {
        int a = a0 + wave * 8 + j;
        float acc = 0.f;
        const float* r0 = w0 + (size_t)a * X0_;
        for (int k = lane; k < X0_; k += 64) acc += r0[k] * xs[k];
        const float* r1 = w1 + (size_t)a * X1_;
        for (int k = lane; k < X1_; k += 64) acc += r1[k] * xs[X0_ + k];
        const float* r2 = w2 + (size_t)a * X2_;
        for (int k = lane; k < X2_; k += 64) acc += r2[k] * xs[X0_ + X1_ + k];
        for (int off = 32; off; off >>= 1) acc += __shfl_down(acc, off, 64);
        if (lane == 0) ctx[b * A_ + a] = acc + bias[a];
    }
}

// ---------------- K2: 128x128 GEMM -> partial scores (fused fp32->bf16 A) --
// XCD-grouped swizzle: the 4 nblk blocks of one (b,mt) tile share the same
// blockIdx%8 (same XCD L2) and are dispatched within 32 IDs of each other,
// so the 512 KB fp32 A-tile is fetched from HBM once and L2-hit 3x instead
// of being fetched by 4 different XCDs. Bijective on [0,4096).
// Block computes Ah tile [128 s] x [128 a]; epilogue: relu(Ah+ctx)*v reduced
// over the 128 a -> partial[nblk][b][s]. A is reg-staged from fp32 hidden
// (global->reg->cvt->LDS), software-pipelined one K-step ahead. B (whb, 1 MB,
// L2-resident) stays on the global_load_lds width=16 path.
__launch_bounds__(256, 2)
__global__ void k_scores(const float* __restrict__ hidden, const unsigned short* __restrict__ whb,
                         const float* __restrict__ ctx, const float* __restrict__ vw,
                         const int* __restrict__ lengths, float* __restrict__ partial) {
    int g = blockIdx.x;
    int xcd = g & 7;
    int i4 = g >> 3;              // 0..511 within this XCD's dispatch share
    int nblk = i4 & 3;
    int grp = xcd * 128 + (i4 >> 2);  // tile group 0..1023
    int b = grp >> 4;
    int mt = grp & 15;
    int s0 = mt * 128;
    if (s0 >= lengths[b]) return;
    int n0b = nblk * 128;

    __shared__ unsigned short As[128 * 32];  // [row][k] bf16, rows 64B
    __shared__ unsigned short Bs[128 * 32];  // [n][k] bf16
    __shared__ float sred[4][64];

    int t = threadIdx.x;
    int wv = t >> 6, lane = t & 63;
    int nl = lane & 15, quad = lane >> 4;
    int wm0 = (wv & 1) * 64;
    int wn0 = (wv >> 1) * 64;

    // A-chunk mapping: chunk c = 16B of As (row = c>>2, k-quarter = c&3).
    int c0 = wv * 64 + lane;    // chunks 0..255
    int c1 = c0 + 256;          // chunks 256..511
    const float* abase = hidden + (size_t)(b * S_ + s0) * H_;
    const unsigned short* bbase = whb + (size_t)n0b * H_;
    size_t aoff0 = (size_t)(c0 >> 2) * H_ + (c0 & 3) * 8;
    size_t aoff1 = (size_t)(c1 >> 2) * H_ + (c1 & 3) * 8;

    // prologue: prefetch k0=0 A-chunks into regs
    float4 a0a = *(const float4*)(abase + aoff0);
    float4 a0b = *(const float4*)(abase + aoff0 + 4);
    float4 a1a = *(const float4*)(abase + aoff1);
    float4 a1b = *(const float4*)(abase + aoff1 + 4);

    floatx4 acc[4][4];
#pragma unroll
    for (int i = 0; i < 4; i++)
#pragma unroll
        for (int j = 0; j < 4; j++) acc[i][j] = (floatx4){0.f, 0.f, 0.f, 0.f};

    for (int k0 = 0; k0 < H_; k0 += 32) {
        // stage B first (start its vmcnt latency early)
#pragma unroll
        for (int i = 0; i < 2; i++) {
            int c = wv * 64 + i * 256 + lane;
            const unsigned short* gb = bbase + (size_t)(c >> 2) * H_ + k0 + (c & 3) * 8;
            __builtin_amdgcn_global_load_lds((glb_cv*)gb,
                (lds_v*)(Bs + (wv * 64 + i * 256) * 8), 16, 0, 0);
        }
        // convert prefetched A regs -> bf16, write LDS (conflict-free linear b128)
        short8 pa, pb;
        pa[0] = hwbf(a0a.x); pa[1] = hwbf(a0a.y); pa[2] = hwbf(a0a.z); pa[3] = hwbf(a0a.w);
        pa[4] = hwbf(a0b.x); pa[5] = hwbf(a0b.y); pa[6] = hwbf(a0b.z); pa[7] = hwbf(a0b.w);
        pb[0] = hwbf(a1a.x); pb[1] = hwbf(a1a.y); pb[2] = hwbf(a1a.z); pb[3] = hwbf(a1a.w);
        pb[4] = hwbf(a1b.x); pb[5] = hwbf(a1b.y); pb[6] = hwbf(a1b.z); pb[7] = hwbf(a1b.w);
        *(short8*)&As[c0 * 8] = pa;
        *(short8*)&As[c1 * 8] = pb;
        __syncthreads();  // drains vmcnt (B) + lgkm (A writes)

        // prefetch A for next K-step: issue now, consumed after next barrier,
        // latency hides under the ds_read+MFMA below.
        if (k0 + 32 < H_) {
            a0a = *(const float4*)(abase + aoff0 + k0 + 32);
            a0b = *(const float4*)(abase + aoff0 + k0 + 36);
            a1a = *(const float4*)(abase + aoff1 + k0 + 32);
            a1b = *(const float4*)(abase + aoff1 + k0 + 36);
        }

        short8 af[4];
#pragma unroll
        for (int m = 0; m < 4; m++)
            af[m] = *(const short8*)&As[(wm0 + m * 16 + nl) * 32 + quad * 8];
#pragma unroll
        for (int n = 0; n < 4; n++) {
            short8 bfr = *(const short8*)&Bs[(wn0 + n * 16 + nl) * 32 + quad * 8];
            bf16x8 bfv = __builtin_bit_cast(bf16x8, bfr);
#pragma unroll
            for (int m = 0; m < 4; m++) {
                bf16x8 afv = __builtin_bit_cast(bf16x8, af[m]);
                acc[m][n] = __builtin_amdgcn_mfma_f32_16x16x32_bf16(afv, bfv, acc[m][n], 0, 0, 0);
            }
        }
        __syncthreads();  // protect LDS before next stage
    }

    // epilogue: relu(acc + ctx)*v, reduce over this block's 128 n
    float cv[4], cc[4];
#pragma unroll
    for (int n = 0; n < 4; n++) {
        int gn = n0b + wn0 + n * 16 + nl;
        cv[n] = vw[gn];
        cc[n] = ctx[b * A_ + gn];
    }
#pragma unroll
    for (int m = 0; m < 4; m++) {
#pragma unroll
        for (int r = 0; r < 4; r++) {
            float sv = 0.f;
#pragma unroll
            for (int n = 0; n < 4; n++) {
                float x = acc[m][n][r] + cc[n];
                sv += (x > 0.f) ? x * cv[n] : 0.f;
            }
#pragma unroll
            for (int off = 1; off < 16; off <<= 1) sv += __shfl_xor(sv, off, 16);
            if (nl == 0) sred[wv][m * 16 + quad * 4 + r] = sv;
        }
    }
    __syncthreads();
    if (t < 128) {
        int h = t >> 6;
        float s = sred[h][t & 63] + sred[h + 2][t & 63];
        partial[((size_t)nblk * B_ + b) * S_ + s0 + t] = s;
    }
}

// ---------------- K3: sum partials, masked softmax over S per b ------------
__global__ void k_softmax(const float* __restrict__ partial, const int* __restrict__ lengths,
                          float* __restrict__ scores, float* __restrict__ probs) {
    int b = blockIdx.x;
    int len = lengths[b];
    int t = threadIdx.x;
    __shared__ float red[256];
    float mx = -1e30f;
    for (int s = t; s < len; s += 256) {
        float sc = partial[(size_t)b * S_ + s] + partial[((size_t)B_ + b) * S_ + s] +
                   partial[((size_t)2 * B_ + b) * S_ + s] + partial[((size_t)3 * B_ + b) * S_ + s];
        scores[b * S_ + s] = sc;
        mx = fmaxf(mx, sc);
    }
    red[t] = mx; __syncthreads();
    for (int off = 128; off; off >>= 1) {
        if (t < off) red[t] = fmaxf(red[t], red[t + off]);
        __syncthreads();
    }
    mx = red[0]; __syncthreads();
    float sum = 0.f;
    for (int s = t; s < len; s += 256) sum += __expf(scores[b * S_ + s] - mx);
    red[t] = sum; __syncthreads();
    for (int off = 128; off; off >>= 1) {
        if (t < off) red[t] += red[t + off];
        __syncthreads();
    }
    float inv = 1.f / red[0];
    for (int s = t; s < S_; s += 256)
        probs[b * S_ + s] = (s < len) ? __expf(scores[b * S_ + s] - mx) * inv : 0.f;
}

// ---------------- K4: partial_out[ch][b][h] = sum_{s in chunk} p[s]*hidden -
__global__ void k_weighted(const float* __restrict__ hidden, const float* __restrict__ probs,
                           const int* __restrict__ lengths, float* __restrict__ partial) {
    int blk = blockIdx.x;
    int b = blk >> 4, ch = blk & 15;
    int len = lengths[b];
    int s0 = ch * 128;
    if (s0 >= len) return;
    int send = min(s0 + 128, len);
    int t = threadIdx.x;
    float4 acc = {0.f, 0.f, 0.f, 0.f};
    const float* hb = hidden + (size_t)(b * S_ + s0) * H_ + t * 4;
    const float* pb = probs + b * S_;
    int s = s0;
    for (; s + 1 < send; s += 2) {
        float p0 = pb[s], p1 = pb[s + 1];
        float4 h0 = *(const float4*)hb;
        float4 h1 = *(const float4*)(hb + H_);
        acc.x += p0 * h0.x + p1 * h1.x;
        acc.y += p0 * h0.y + p1 * h1.y;
        acc.z += p0 * h0.z + p1 * h1.z;
        acc.w += p0 * h0.w + p1 * h1.w;
        hb += 2 * H_;
    }
    if (s < send) {
        float p = pb[s];
        float4 h = *(const float4*)hb;
        acc.x += p * h.x; acc.y += p * h.y; acc.z += p * h.z; acc.w += p * h.w;
    }
    *(float4*)(partial + ((size_t)ch * B_ + b) * H_ + t * 4) = acc;
}

// ---------------- K5: out[b][h] = sum over valid chunks -------------------
__global__ void k_reduce(const float* __restrict__ partial, const int* __restrict__ lengths,
                         float* __restrict__ out) {
    int i = blockIdx.x * 256 + threadIdx.x;
    int b = i >> 10;
    int h = i & 1023;
    int len = lengths[b];
    int nch = (len + 127) >> 7;
    float s = 0.f;
    for (int c = 0; c < nch; c++) s += partial[((size_t)c * B_ + b) * H_ + h];
    out[i] = s;
}

extern "C" void kernel_launch(void* const* d_in, const int* in_sizes, int n_in,
                              void* d_out, int out_size, void* d_ws, size_t ws_size,
                              hipStream_t stream) {
    const float* hidden = (const float*)d_in[0];
    const float* x0 = (const float*)d_in[1];
    const float* x1 = (const float*)d_in[2];
    const float* x2 = (const float*)d_in[3];
    const int* lengths = (const int*)d_in[4];
    const float* wh_w = (const float*)d_in[5];
    const float* wh_b = (const float*)d_in[6];
    const float* w0_w = (const float*)d_in[7];
    const float* w1_w = (const float*)d_in[8];
    const float* w2_w = (const float*)d_in[9];
    const float* v_w = (const float*)d_in[10];

    float* out = (float*)d_out;    // [B,H]
    float* probs = out + B_ * H_;  // [B,S]

    char* ws = (char*)d_ws;
    float* ctx = (float*)ws;                                    // 128 KB
    unsigned short* whb = (unsigned short*)(ws + (1 << 17));    // 1 MB
    float* scores = (float*)(ws + (1 << 17) + (1 << 20));       // 512 KB
    float* pscore = (float*)(ws + (1 << 17) + (1 << 20) + (1 << 19));          // 2 MB  [4][B][S]
    float* pout = (float*)(ws + (1 << 17) + (1 << 20) + (1 << 19) + (1 << 21)); // 4 MB  [16][B][H]

    k_convert_wh<<<dim3(A_ * H_ / 1024), dim3(256), 0, stream>>>(wh_w, whb);
    k_ctx<<<dim3(B_ * (A_ / 32)), dim3(256), 0, stream>>>(x0, x1, x2, w0_w, w1_w, w2_w, wh_b, ctx);
    k_scores<<<dim3(B_ * 64), dim3(256), 0, stream>>>(hidden, whb, ctx, v_w, lengths, pscore);
    k_softmax<<<dim3(B_), dim3(256), 0, stream>>>(pscore, lengths, scores, probs);
    k_weighted<<<dim3(B_ * 16), dim3(256), 0, stream>>>(hidden, probs, lengths, pout);
    k_reduce<<<dim3(B_ * H_ / 256), dim3(256), 0, stream>>>(pout, lengths, out);
}

// Round 3
// 829.722 us; speedup vs baseline: 1.1057x; 1.0208x over previous
//
#include <hip/hip_runtime.h>
#include <hip/hip_bf16.h>
#include <stdint.h>

#define B_ 64
#define S_ 2048
#define H_ 1024
#define X0_ 1024
#define X1_ 512
#define X2_ 512
#define A_ 512

typedef __attribute__((ext_vector_type(8))) short short8;
typedef __attribute__((ext_vector_type(8))) __bf16 bf16x8;
typedef __attribute__((ext_vector_type(4))) float floatx4;

typedef __attribute__((address_space(1))) const void glb_cv;
typedef __attribute__((address_space(3))) void lds_v;

__device__ inline unsigned short f2bf(float f) {
    union { float f; unsigned u; } v; v.f = f;
    unsigned u = v.u;
    unsigned r = u + 0x7FFF + ((u >> 16) & 1);  // RNE
    return (unsigned short)(r >> 16);
}

// HW bf16 convert (RNE) — compiler pairs these into v_cvt_pk_bf16_f32.
__device__ inline short hwbf(float f) {
    return (short)__builtin_bit_cast(unsigned short, __float2bfloat16(f));
}

// ---------------- K0a: convert Wh (A x H fp32) -> bf16 bits ----------------
__global__ void k_convert_wh(const float* __restrict__ wh, unsigned short* __restrict__ whb) {
    int i = (blockIdx.x * 256 + threadIdx.x) * 4;
    float4 f = *(const float4*)(wh + i);
    ushort4 o;
    o.x = f2bf(f.x); o.y = f2bf(f.y); o.z = f2bf(f.z); o.w = f2bf(f.w);
    *(ushort4*)(whb + i) = o;
}

// ---------------- K1: ctx[b,a] = bias[a] + W0 x0 + W1 x1 + W2 x2 ----------
__global__ void k_ctx(const float* __restrict__ x0, const float* __restrict__ x1,
                      const float* __restrict__ x2, const float* __restrict__ w0,
                      const float* __restrict__ w1, const float* __restrict__ w2,
                      const float* __restrict__ bias, float* __restrict__ ctx) {
    __shared__ float xs[X0_ + X1_ + X2_];
    int b = blockIdx.x >> 4;
    int a0 = (blockIdx.x & 15) << 5;
    int t = threadIdx.x;
    for (int i = t; i < X0_; i += 256) xs[i] = x0[b * X0_ + i];
    for (int i = t; i < X1_; i += 256) xs[X0_ + i] = x1[b * X1_ + i];
    for (int i = t; i < X2_; i += 256) xs[X0_ + X1_ + i] = x2[b * X2_ + i];
    __syncthreads();
    int wave = t >> 6, lane = t & 63;
    for (int j = 0; j < 8; j++) {
        int a = a0 + wave * 8 + j;
        float acc = 0.f;
        const float* r0 = w0 + (size_t)a * X0_;
        for (int k = lane; k < X0_; k += 64) acc += r0[k] * xs[k];
        const float* r1 = w1 + (size_t)a * X1_;
        for (int k = lane; k < X1_; k += 64) acc += r1[k] * xs[X0_ + k];
        const float* r2 = w2 + (size_t)a * X2_;
        for (int k = lane; k < X2_; k += 64) acc += r2[k] * xs[X0_ + X1_ + k];
        for (int off = 32; off; off >>= 1) acc += __shfl_down(acc, off, 64);
        if (lane == 0) ctx[b * A_ + a] = acc + bias[a];
    }
}

// ---------------- K2: 128x512 GEMM tile -> final scores --------------------
// One block per (b,mt): computes the FULL Ah row-block [128 s] x [512 a],
// so the A-tile is staged once per K-step (was 4x across nblk blocks) and
// each 2-barrier K-step runs 32 MFMA/wave (2x the old density; barrier
// drain amortized). Epilogue reduces relu(Ah+ctx)*v over all 512 a and
// writes final scores directly (no partial buffer).
// 8 waves as 2M x 4N: wave (wm=wv&1, wn=wv>>1) owns [64 s] x [128 a],
// acc[4][8] fragments of 16x16. A reg-staged fp32->bf16 (1 chunk/thread),
// one K-step prefetch ahead; B via global_load_lds width=16 (whb 1 MB,
// L2-resident per XCD). XCD swizzle keeps each XCD on a contiguous b-range.
__launch_bounds__(512, 2)
__global__ void k_scores(const float* __restrict__ hidden, const unsigned short* __restrict__ whb,
                         const float* __restrict__ ctx, const float* __restrict__ vw,
                         const int* __restrict__ lengths, float* __restrict__ scores) {
    int g = blockIdx.x;
    int grp = (g & 7) * 128 + (g >> 3);  // bijective on [0,1024): same-XCD = contiguous groups
    int b = grp >> 4;
    int mt = grp & 15;
    int s0 = mt * 128;
    if (s0 >= lengths[b]) return;

    __shared__ unsigned short As[128 * 32];  // [row][k] bf16, rows 64B
    __shared__ unsigned short Bs[512 * 32];  // [n][k] bf16, rows 64B (32 KB)
    __shared__ float sred[8][64];

    int t = threadIdx.x;
    int wv = t >> 6, lane = t & 63;
    int nl = lane & 15, quad = lane >> 4;
    int wm0 = (wv & 1) * 64;       // M offset of this wave
    int wn0 = (wv >> 1) * 128;     // N offset of this wave

    // A-chunk mapping: chunk c = 16B of As (row = c>>2, k-quarter = c&3); c = t.
    const float* abase = hidden + (size_t)(b * S_ + s0) * H_;
    size_t aoff = (size_t)(t >> 2) * H_ + (t & 3) * 8;

    // prologue: prefetch k0=0 A-chunk into regs
    float4 a0a = *(const float4*)(abase + aoff);
    float4 a0b = *(const float4*)(abase + aoff + 4);

    floatx4 acc[4][8];
#pragma unroll
    for (int i = 0; i < 4; i++)
#pragma unroll
        for (int j = 0; j < 8; j++) acc[i][j] = (floatx4){0.f, 0.f, 0.f, 0.f};

    for (int k0 = 0; k0 < H_; k0 += 32) {
        // stage B: 512 rows x 64B = 2048 16B-chunks; 4 per thread via gl_lds
#pragma unroll
        for (int i = 0; i < 4; i++) {
            int c = wv * 64 + i * 512 + lane;
            const unsigned short* gb = whb + (size_t)(c >> 2) * H_ + k0 + (c & 3) * 8;
            __builtin_amdgcn_global_load_lds((glb_cv*)gb,
                (lds_v*)(Bs + (wv * 64 + i * 512) * 8), 16, 0, 0);
        }
        // convert prefetched A regs -> bf16, write LDS (linear b128)
        short8 pa;
        pa[0] = hwbf(a0a.x); pa[1] = hwbf(a0a.y); pa[2] = hwbf(a0a.z); pa[3] = hwbf(a0a.w);
        pa[4] = hwbf(a0b.x); pa[5] = hwbf(a0b.y); pa[6] = hwbf(a0b.z); pa[7] = hwbf(a0b.w);
        *(short8*)&As[t * 8] = pa;
        __syncthreads();  // drains vmcnt (B) + lgkm (A writes)

        // prefetch A for next K-step; latency hides under ds_read+MFMA below.
        if (k0 + 32 < H_) {
            a0a = *(const float4*)(abase + aoff + k0 + 32);
            a0b = *(const float4*)(abase + aoff + k0 + 36);
        }

        short8 af[4];
#pragma unroll
        for (int m = 0; m < 4; m++)
            af[m] = *(const short8*)&As[(wm0 + m * 16 + nl) * 32 + quad * 8];
#pragma unroll
        for (int n = 0; n < 8; n++) {
            short8 bfr = *(const short8*)&Bs[(wn0 + n * 16 + nl) * 32 + quad * 8];
            bf16x8 bfv = __builtin_bit_cast(bf16x8, bfr);
#pragma unroll
            for (int m = 0; m < 4; m++) {
                bf16x8 afv = __builtin_bit_cast(bf16x8, af[m]);
                acc[m][n] = __builtin_amdgcn_mfma_f32_16x16x32_bf16(afv, bfv, acc[m][n], 0, 0, 0);
            }
        }
        __syncthreads();  // protect LDS before next stage
    }

    // epilogue: relu(acc + ctx)*v, reduce over this wave's 128 n
    float cv[8], cc[8];
#pragma unroll
    for (int n = 0; n < 8; n++) {
        int gn = wn0 + n * 16 + nl;
        cv[n] = vw[gn];
        cc[n] = ctx[b * A_ + gn];
    }
#pragma unroll
    for (int m = 0; m < 4; m++) {
#pragma unroll
        for (int r = 0; r < 4; r++) {
            float sv = 0.f;
#pragma unroll
            for (int n = 0; n < 8; n++) {
                float x = acc[m][n][r] + cc[n];
                sv += (x > 0.f) ? x * cv[n] : 0.f;
            }
#pragma unroll
            for (int off = 1; off < 16; off <<= 1) sv += __shfl_xor(sv, off, 16);
            if (nl == 0) sred[wv][m * 16 + quad * 4 + r] = sv;
        }
    }
    __syncthreads();
    // rows 0-63 owned by waves {0,2,4,6} (wm=0), rows 64-127 by {1,3,5,7}
    if (t < 128) {
        int h = t >> 6, row = t & 63;
        float s = sred[h][row] + sred[2 + h][row] + sred[4 + h][row] + sred[6 + h][row];
        scores[(size_t)b * S_ + s0 + t] = s;
    }
}

// ---------------- K3: masked softmax over S per b --------------------------
__global__ void k_softmax(const float* __restrict__ scores, const int* __restrict__ lengths,
                          float* __restrict__ probs) {
    int b = blockIdx.x;
    int len = lengths[b];
    int t = threadIdx.x;
    __shared__ float red[256];
    float mx = -1e30f;
    for (int s = t; s < len; s += 256) mx = fmaxf(mx, scores[(size_t)b * S_ + s]);
    red[t] = mx; __syncthreads();
    for (int off = 128; off; off >>= 1) {
        if (t < off) red[t] = fmaxf(red[t], red[t + off]);
        __syncthreads();
    }
    mx = red[0]; __syncthreads();
    float sum = 0.f;
    for (int s = t; s < len; s += 256) sum += __expf(scores[(size_t)b * S_ + s] - mx);
    red[t] = sum; __syncthreads();
    for (int off = 128; off; off >>= 1) {
        if (t < off) red[t] += red[t + off];
        __syncthreads();
    }
    float inv = 1.f / red[0];
    for (int s = t; s < S_; s += 256)
        probs[b * S_ + s] = (s < len) ? __expf(scores[(size_t)b * S_ + s] - mx) * inv : 0.f;
}

// ---------------- K4: partial_out[ch][b][h] = sum_{s in chunk} p[s]*hidden -
__global__ void k_weighted(const float* __restrict__ hidden, const float* __restrict__ probs,
                           const int* __restrict__ lengths, float* __restrict__ partial) {
    int blk = blockIdx.x;
    int b = blk >> 4, ch = blk & 15;
    int len = lengths[b];
    int s0 = ch * 128;
    if (s0 >= len) return;
    int send = min(s0 + 128, len);
    int t = threadIdx.x;
    float4 acc = {0.f, 0.f, 0.f, 0.f};
    const float* hb = hidden + (size_t)(b * S_ + s0) * H_ + t * 4;
    const float* pb = probs + b * S_;
    int s = s0;
    for (; s + 1 < send; s += 2) {
        float p0 = pb[s], p1 = pb[s + 1];
        float4 h0 = *(const float4*)hb;
        float4 h1 = *(const float4*)(hb + H_);
        acc.x += p0 * h0.x + p1 * h1.x;
        acc.y += p0 * h0.y + p1 * h1.y;
        acc.z += p0 * h0.z + p1 * h1.z;
        acc.w += p0 * h0.w + p1 * h1.w;
        hb += 2 * H_;
    }
    if (s < send) {
        float p = pb[s];
        float4 h = *(const float4*)hb;
        acc.x += p * h.x; acc.y += p * h.y; acc.z += p * h.z; acc.w += p * h.w;
    }
    *(float4*)(partial + ((size_t)ch * B_ + b) * H_ + t * 4) = acc;
}

// ---------------- K5: out[b][h] = sum over valid chunks -------------------
__global__ void k_reduce(const float* __restrict__ partial, const int* __restrict__ lengths,
                         float* __restrict__ out) {
    int i = blockIdx.x * 256 + threadIdx.x;
    int b = i >> 10;
    int h = i & 1023;
    int len = lengths[b];
    int nch = (len + 127) >> 7;
    float s = 0.f;
    for (int c = 0; c < nch; c++) s += partial[((size_t)c * B_ + b) * H_ + h];
    out[i] = s;
}

extern "C" void kernel_launch(void* const* d_in, const int* in_sizes, int n_in,
                              void* d_out, int out_size, void* d_ws, size_t ws_size,
                              hipStream_t stream) {
    const float* hidden = (const float*)d_in[0];
    const float* x0 = (const float*)d_in[1];
    const float* x1 = (const float*)d_in[2];
    const float* x2 = (const float*)d_in[3];
    const int* lengths = (const int*)d_in[4];
    const float* wh_w = (const float*)d_in[5];
    const float* wh_b = (const float*)d_in[6];
    const float* w0_w = (const float*)d_in[7];
    const float* w1_w = (const float*)d_in[8];
    const float* w2_w = (const float*)d_in[9];
    const float* v_w = (const float*)d_in[10];

    float* out = (float*)d_out;    // [B,H]
    float* probs = out + B_ * H_;  // [B,S]

    char* ws = (char*)d_ws;
    float* ctx = (float*)ws;                                    // 128 KB
    unsigned short* whb = (unsigned short*)(ws + (1 << 17));    // 1 MB
    float* scores = (float*)(ws + (1 << 17) + (1 << 20));       // 512 KB
    float* pout = (float*)(ws + (1 << 17) + (1 << 20) + (1 << 19)); // 4 MB [16][B][H]

    k_convert_wh<<<dim3(A_ * H_ / 1024), dim3(256), 0, stream>>>(wh_w, whb);
    k_ctx<<<dim3(B_ * (A_ / 32)), dim3(256), 0, stream>>>(x0, x1, x2, w0_w, w1_w, w2_w, wh_b, ctx);
    k_scores<<<dim3(B_ * 16), dim3(512), 0, stream>>>(hidden, whb, ctx, v_w, lengths, scores);
    k_softmax<<<dim3(B_), dim3(256), 0, stream>>>(scores, lengths, probs);
    k_weighted<<<dim3(B_ * 16), dim3(256), 0, stream>>>(hidden, probs, lengths, pout);
    k_reduce<<<dim3(B_ * H_ / 256), dim3(256), 0, stream>>>(pout, lengths, out);
}